// Round 5
// baseline (223.375 us; speedup 1.0000x reference)
//
#include <hip/hip_runtime.h>

#define D 16
#define MI 511                  // interior rows/cols of K grid
#define NSTEPS (MI + 63)        // 574 pipeline steps per pass (skew-1)
#define SY_STRIDE 18            // floats/row; zero conflicts measured @ skew-1

typedef float v2f __attribute__((ext_vector_type(2)));

// One wave per (pair, batch). Two passes of 256 grid-rows each, 4 rows/lane.
// Pass A: rows 1..256, lane63 parks bottom row K[256][c] in smid[].
// Pass B: rows 257..511, lane0 pulls its top boundary from smid[].
// Skew-1 pipeline; bottom-row handoff shfl issued post-compute -> 1 step slack.
__global__ __launch_bounds__(64, 1)
void sig_pde_kernel(const float* __restrict__ X, const float* __restrict__ Y,
                    float* __restrict__ out) {
    __shared__ float sy[MI * SY_STRIDE];   // dY rows, ~36.8 KB
    __shared__ float smid[MI + 1];         // K[256][c], 2 KB

    const int idx  = blockIdx.x;
    const int pair = idx >> 7;             // 0: XX, 1: YY, 2: XY
    const int a    = idx & 127;
    const float* Pp = (pair == 1) ? Y : X;
    const float* Qp = (pair == 0) ? X : Y;
    const float* prow = Pp + (size_t)a * 512 * D;
    const float* qrow = Qp + (size_t)a * 512 * D;

    const int l = threadIdx.x;

    // Stage dY rows into LDS (one-time).
    for (int j = l; j < MI; j += 64) {
        const float4* r1 = (const float4*)(qrow + (size_t)(j + 1) * D);
        const float4* r0 = (const float4*)(qrow + (size_t)j * D);
        #pragma unroll
        for (int q = 0; q < 4; ++q) {
            float4 v1 = r1[q], v0 = r0[q];
            sy[j * SY_STRIDE + 4*q + 0] = v1.x - v0.x;
            sy[j * SY_STRIDE + 4*q + 1] = v1.y - v0.y;
            sy[j * SY_STRIDE + 4*q + 2] = v1.z - v0.z;
            sy[j * SY_STRIDE + 4*q + 3] = v1.w - v0.w;
        }
    }
    __syncthreads();

    v2f xr[4][8];          // 4 dX rows as float2 pairs (64 VGPRs)
    float kleft[4];        // K[row_r][c-1]
    float arrived;         // K[top-1][c]   for the upcoming step
    float arrivedP;        // K[top-1][c-1]
    v2f yA[8], yB[8];      // double-buffered dY row

#define LOADX(RBASE) do {                                                     \
        _Pragma("unroll")                                                     \
        for (int r_ = 0; r_ < 4; ++r_) {                                      \
            int gi_ = (RBASE) + r_;                                           \
            if (gi_ > MI - 1) gi_ = MI - 1;                                   \
            const float4* p1_ = (const float4*)(prow + (size_t)(gi_ + 1) * D);\
            const float4* p0_ = (const float4*)(prow + (size_t)gi_ * D);      \
            _Pragma("unroll")                                                 \
            for (int q_ = 0; q_ < 4; ++q_) {                                  \
                float4 v1_ = p1_[q_], v0_ = p0_[q_];                          \
                v2f t0_; t0_[0] = v1_.x - v0_.x; t0_[1] = v1_.y - v0_.y;      \
                v2f t1_; t1_[0] = v1_.z - v0_.z; t1_[1] = v1_.w - v0_.w;      \
                xr[r_][2*q_ + 0] = t0_;                                       \
                xr[r_][2*q_ + 1] = t1_;                                       \
            }                                                                 \
        }                                                                     \
    } while (0)

#define LOADY(CC, BUF) do {                                                   \
        int cc_ = (CC); cc_ = cc_ < 1 ? 1 : (cc_ > MI ? MI : cc_);            \
        const float* yp_ = &sy[(size_t)(cc_ - 1) * SY_STRIDE];                \
        _Pragma("unroll")                                                     \
        for (int q_ = 0; q_ < 8; ++q_) BUF[q_] = *(const v2f*)(yp_ + 2*q_);   \
    } while (0)

#define STEP(S, YC, YN, PASSB) do {                                           \
        const int c_ = (S) - l + 1;                                           \
        LOADY(c_ + 1, YN);                 /* prefetch next column */         \
        if (c_ >= 1 && c_ <= MI) {                                            \
            float know_ = arrived;         /* K[top-1][c]   */                \
            float kd_   = arrivedP;        /* K[top-1][c-1] */                \
            _Pragma("unroll")                                                 \
            for (int r_ = 0; r_ < 4; ++r_) {                                  \
                v2f acc_; acc_[0] = -1.0f; acc_[1] = 0.0f;                    \
                _Pragma("unroll")                                             \
                for (int q_ = 0; q_ < 8; ++q_)                                \
                    acc_ = __builtin_elementwise_fma(xr[r_][q_], YC[q_], acc_);\
                float dotm1_ = acc_[0] + acc_[1];                             \
                float kl_ = kleft[r_];                                        \
                float v_  = fmaf(kd_, dotm1_, know_ + kl_);                   \
                kd_ = kl_; know_ = v_; kleft[r_] = v_;                        \
            }                                                                 \
            if (!(PASSB) && l == 63) smid[c_] = kleft[3];  /* park K[256][c] */\
        }                                                                     \
        arrivedP = arrived;                                                   \
        {                                                                     \
            float inc_ = __shfl_up(kleft[3], 1, 64);   /* bottom @ col c+1 */ \
            if (PASSB) {                                                      \
                int mi_ = (S) + 2; if (mi_ > MI) mi_ = MI;                    \
                float mv_ = smid[mi_];          /* uniform -> broadcast */    \
                arrived = (l == 0) ? mv_ : inc_;                              \
            } else {                                                          \
                arrived = (l == 0) ? 1.0f : inc_;                             \
            }                                                                 \
        }                                                                     \
    } while (0)

    // ---------------- Pass A: grid rows 1..256 ----------------
    LOADX(4 * l);                           // dX idx 4l..4l+3 (0..255)
    #pragma unroll
    for (int r = 0; r < 4; ++r) kleft[r] = 1.0f;
    arrived = 1.0f; arrivedP = 1.0f;
    LOADY(1 - l, yA);
    for (int s = 0; s < NSTEPS; s += 2) {
        STEP(s,     yA, yB, 0);
        STEP(s + 1, yB, yA, 0);
    }

    // ---------------- Pass B: grid rows 257..511 ----------------
    LOADX(256 + 4 * l);                     // dX idx 256..511 -> clamp 510
    #pragma unroll
    for (int r = 0; r < 4; ++r) kleft[r] = 1.0f;
    arrivedP = 1.0f;                        // = K[256][0]
    arrived  = (l == 0) ? smid[1] : 1.0f;   // K[256][1] for lane 0
    LOADY(1 - l, yA);
    for (int s = 0; s < NSTEPS; s += 2) {
        STEP(s,     yA, yB, 1);
        STEP(s + 1, yB, yA, 1);
    }

#undef STEP
#undef LOADY
#undef LOADX

    // K[511][511]: lane 63 owns rows 509..512; r=2 is row 511.
    if (l == 63) out[idx] = kleft[2];
}

__global__ void sig_reduce_kernel(const float* __restrict__ ws,
                                  float* __restrict__ out) {
    const int a = threadIdx.x;  // 128 threads
    float v = ws[a] + ws[128 + a] - 2.0f * ws[256 + a];
    #pragma unroll
    for (int off = 32; off >= 1; off >>= 1) v += __shfl_down(v, off, 64);
    __shared__ float partial[2];
    if ((a & 63) == 0) partial[a >> 6] = v;
    __syncthreads();
    if (a == 0) out[0] = (partial[0] + partial[1]) * (1.0f / 128.0f);
}

extern "C" void kernel_launch(void* const* d_in, const int* in_sizes, int n_in,
                              void* d_out, int out_size, void* d_ws, size_t ws_size,
                              hipStream_t stream) {
    const float* X = (const float*)d_in[0];
    const float* Y = (const float*)d_in[1];
    float* out = (float*)d_out;
    float* ws  = (float*)d_ws;   // 384 floats: [pair*128 + a]

    sig_pde_kernel<<<dim3(384), dim3(64), 0, stream>>>(X, Y, ws);
    sig_reduce_kernel<<<dim3(1), dim3(128), 0, stream>>>(ws, out);
}

// Round 6
// 211.009 us; speedup vs baseline: 1.0586x; 1.0586x over previous
//
#include <hip/hip_runtime.h>

#define D 16
#define MI 511                  // interior rows/cols of K grid
#define NSTEPS (MI + 126)       // 637 steps per pass (skew-2, 64 lanes)
#define SY_STRIDE 18            // floats/row; 8B-aligned rows for b64 reads

typedef float v2f __attribute__((ext_vector_type(2)));

__device__ __forceinline__ int iclamp(int v, int lo, int hi) {
    return v < lo ? lo : (v > hi ? hi : v);
}

// One wave per (pair, batch). Two passes of 256 grid-rows, 4 rows/lane.
// Skew-2 wavefront: lane l at step s computes column c = s - 2l + 1.
// Branchless body (cndmask boundaries); bpermute handoff has a full step
// of slack; pass-B smid boundary value prefetched one step ahead.
template<int PASSB>
__device__ __forceinline__ float run_pass(const float* __restrict__ prow,
                                          const float* __restrict__ sy,
                                          float* __restrict__ smid, int l)
{
    // dX rows for this pass (static-indexed -> registers).
    v2f xr[4][8];
    {
        const int rbase = (PASSB ? 256 : 0) + 4 * l;
        #pragma unroll
        for (int r = 0; r < 4; ++r) {
            int gi = rbase + r; if (gi > MI - 1) gi = MI - 1;   // fake row clamp
            const float4* p1 = (const float4*)(prow + (size_t)(gi + 1) * D);
            const float4* p0 = (const float4*)(prow + (size_t)gi * D);
            #pragma unroll
            for (int q = 0; q < 4; ++q) {
                float4 v1 = p1[q], v0 = p0[q];
                v2f t0; t0[0] = v1.x - v0.x; t0[1] = v1.y - v0.y;
                v2f t1; t1[0] = v1.z - v0.z; t1[1] = v1.w - v0.w;
                xr[r][2*q + 0] = t0; xr[r][2*q + 1] = t1;
            }
        }
    }

    float kleft0 = 1.f, kleft1 = 1.f, kleft2 = 1.f, kleft3 = 1.f;
    float arrived  = 1.f;   // K[top-1][c] for the upcoming step
    float arrivedP = 1.f;   // K[top-1][c-1]
    float bot_d1   = 1.f;   // this lane's bottom value, 1 column old
    float smn      = 1.f;   // prefetched smid value (pass B)
    if (PASSB) {
        smn = smid[1];
        if (l == 0) arrived = smn;     // K[256][1] for lane 0's first column
    }

    v2f yA[8], yB[8];
    {   // preload y for step 0 (column 1 - 2l, clamped)
        int cc = iclamp(1 - 2 * l, 1, MI);
        const float* yp = sy + (size_t)(cc - 1) * SY_STRIDE;
        #pragma unroll
        for (int q = 0; q < 8; ++q) yA[q] = *(const v2f*)(yp + 2 * q);
    }

#define STEPB(S, YC, YN) do {                                                 \
        /* 1. handoff shuffle issued at step TOP (full step of slack) */      \
        float incn_ = __shfl_up(bot_d1, 1, 64);                               \
        const int c_ = (S) - 2 * l + 1;                                       \
        /* 2. prefetch next column's y-row */                                 \
        { int cn_ = iclamp(c_ + 1, 1, MI);                                    \
          const float* yp_ = sy + (size_t)(cn_ - 1) * SY_STRIDE;              \
          _Pragma("unroll")                                                   \
          for (int q_ = 0; q_ < 8; ++q_) YN[q_] = *(const v2f*)(yp_ + 2*q_); }\
        /* 3. prefetch pass-B boundary (uniform address, off crit path) */    \
        float smn_new_ = 1.f;                                                 \
        if (PASSB) { int si_ = (S) + 2; if (si_ > MI) si_ = MI;               \
                     smn_new_ = smid[si_]; }                                  \
        /* 4. branchless boundary fixes */                                    \
        const bool at1_ = (c_ == 1);                                          \
        kleft0 = at1_ ? 1.f : kleft0;  kleft1 = at1_ ? 1.f : kleft1;          \
        kleft2 = at1_ ? 1.f : kleft2;  kleft3 = at1_ ? 1.f : kleft3;          \
        arrivedP = (c_ <= 1) ? 1.f : arrivedP;                                \
        /* 5. four dot products, 4-way ILP */                                 \
        float d0_, d1_, d2_, d3_;                                             \
        { v2f a0_; a0_[0] = -1.f; a0_[1] = 0.f;                               \
          v2f a1_ = a0_, a2_ = a0_, a3_ = a0_;                                \
          _Pragma("unroll")                                                   \
          for (int q_ = 0; q_ < 8; ++q_) {                                    \
            a0_ = __builtin_elementwise_fma(xr[0][q_], YC[q_], a0_);          \
            a1_ = __builtin_elementwise_fma(xr[1][q_], YC[q_], a1_);          \
            a2_ = __builtin_elementwise_fma(xr[2][q_], YC[q_], a2_);          \
            a3_ = __builtin_elementwise_fma(xr[3][q_], YC[q_], a3_);          \
          }                                                                   \
          d0_ = a0_[0] + a0_[1]; d1_ = a1_[0] + a1_[1];                       \
          d2_ = a2_[0] + a2_[1]; d3_ = a3_[0] + a3_[1]; }                     \
        /* 6. serial recurrence down the 4 rows */                            \
        { float know_ = arrived, kd_ = arrivedP, v_;                          \
          v_ = fmaf(kd_, d0_, know_ + kleft0); kd_ = kleft0; know_ = v_; kleft0 = v_; \
          v_ = fmaf(kd_, d1_, know_ + kleft1); kd_ = kleft1; know_ = v_; kleft1 = v_; \
          v_ = fmaf(kd_, d2_, know_ + kleft2); kd_ = kleft2; know_ = v_; kleft2 = v_; \
          v_ = fmaf(kd_, d3_, know_ + kleft3); kd_ = kleft3; know_ = v_; kleft3 = v_; } \
        /* 7. pass A: park K[256][c] (garbage slots overwritten later) */     \
        if (!PASSB && l == 63) smid[c_ & 511] = kleft3;                       \
        /* 8. advance the arrived pipeline */                                 \
        arrivedP = arrived;                                                   \
        arrived  = (l == 0) ? (PASSB ? smn : 1.f) : incn_;                    \
        smn      = smn_new_;                                                  \
        bot_d1   = kleft3;                                                    \
    } while (0)

    for (int s = 0; s < NSTEPS - 1; s += 2) {
        STEPB(s,     yA, yB);
        STEPB(s + 1, yB, yA);
    }
    STEPB(NSTEPS - 1, yA, yB);   // s = 636 (even index -> yA current)
#undef STEPB

    return kleft2;   // pass B lane 63: grid row 511
}

__global__ __launch_bounds__(64, 1)
void sig_pde_kernel(const float* __restrict__ X, const float* __restrict__ Y,
                    float* __restrict__ out) {
    __shared__ float sy[MI * SY_STRIDE];   // dY rows, ~36.8 KB
    __shared__ float smid[512];            // K[256][c] relay, 2 KB

    const int idx  = blockIdx.x;
    const int pair = idx >> 7;             // 0: XX, 1: YY, 2: XY
    const int a    = idx & 127;
    const float* Pp = (pair == 1) ? Y : X;
    const float* Qp = (pair == 0) ? X : Y;
    const float* prow = Pp + (size_t)a * 512 * D;
    const float* qrow = Qp + (size_t)a * 512 * D;

    const int l = threadIdx.x;

    // Stage dY rows into LDS (one-time).
    for (int j = l; j < MI; j += 64) {
        const float4* r1 = (const float4*)(qrow + (size_t)(j + 1) * D);
        const float4* r0 = (const float4*)(qrow + (size_t)j * D);
        #pragma unroll
        for (int q = 0; q < 4; ++q) {
            float4 v1 = r1[q], v0 = r0[q];
            sy[j * SY_STRIDE + 4*q + 0] = v1.x - v0.x;
            sy[j * SY_STRIDE + 4*q + 1] = v1.y - v0.y;
            sy[j * SY_STRIDE + 4*q + 2] = v1.z - v0.z;
            sy[j * SY_STRIDE + 4*q + 3] = v1.w - v0.w;
        }
    }
    __syncthreads();

    run_pass<0>(prow, sy, smid, l);                 // rows 1..256
    float r = run_pass<1>(prow, sy, smid, l);       // rows 257..511

    if (l == 63) out[idx] = r;
}

__global__ void sig_reduce_kernel(const float* __restrict__ ws,
                                  float* __restrict__ out) {
    const int a = threadIdx.x;  // 128 threads
    float v = ws[a] + ws[128 + a] - 2.0f * ws[256 + a];
    #pragma unroll
    for (int off = 32; off >= 1; off >>= 1) v += __shfl_down(v, off, 64);
    __shared__ float partial[2];
    if ((a & 63) == 0) partial[a >> 6] = v;
    __syncthreads();
    if (a == 0) out[0] = (partial[0] + partial[1]) * (1.0f / 128.0f);
}

extern "C" void kernel_launch(void* const* d_in, const int* in_sizes, int n_in,
                              void* d_out, int out_size, void* d_ws, size_t ws_size,
                              hipStream_t stream) {
    const float* X = (const float*)d_in[0];
    const float* Y = (const float*)d_in[1];
    float* out = (float*)d_out;
    float* ws  = (float*)d_ws;   // 384 floats: [pair*128 + a]

    sig_pde_kernel<<<dim3(384), dim3(64), 0, stream>>>(X, Y, ws);
    sig_reduce_kernel<<<dim3(1), dim3(128), 0, stream>>>(ws, out);
}

// Round 7
// 207.280 us; speedup vs baseline: 1.0776x; 1.0180x over previous
//
#include <hip/hip_runtime.h>

#define D 16
#define MI 511                   // interior rows/cols of K grid
#define NSTEPS (MI + 63)         // 574 per-wave steps (skew-1)
#define SY_STRIDE 18             // floats/row; zero bank conflicts @ skew-1
#define B_PH 32                  // steps per barrier phase
#define OFF_STEPS 96             // per-wave lag = 64 (lane skew) + B_PH
#define NPHASES ((NSTEPS + 3 * OFF_STEPS + B_PH - 1) / B_PH)   // 27

typedef float v2f __attribute__((ext_vector_type(2)));

// One problem per block, 4 waves. Wave w owns grid rows 128w+1 .. 128w+128
// (2 rows/lane, skew-1: lane l at step s computes column c = s - l + 1).
// Wave w's bottom row (grid row 128(w+1)) is relayed to wave w+1 through a
// 256-entry LDS ring; wave w+1 lags by OFF_STEPS, and a block barrier every
// B_PH steps orders every relay write >=1 barrier before its read.
__global__ __launch_bounds__(256, 1)
void sig_pde_kernel(const float* __restrict__ X, const float* __restrict__ Y,
                    float* __restrict__ out) {
    __shared__ float sy[MI * SY_STRIDE];   // dY rows, ~36.8 KB
    __shared__ float relay[3][256];        // bottom-row rings, 3 KB

    const int idx  = blockIdx.x;
    const int pair = idx >> 7;             // 0: XX, 1: YY, 2: XY
    const int a    = idx & 127;
    const float* Pp = (pair == 1) ? Y : X;
    const float* Qp = (pair == 0) ? X : Y;
    const float* prow = Pp + (size_t)a * 512 * D;
    const float* qrow = Qp + (size_t)a * 512 * D;

    const int tid = threadIdx.x;
    const int w   = tid >> 6;              // wave 0..3
    const int l   = tid & 63;              // lane

    // Stage dY rows into LDS (256 threads cooperate).
    for (int j = tid; j < MI; j += 256) {
        const float4* r1 = (const float4*)(qrow + (size_t)(j + 1) * D);
        const float4* r0 = (const float4*)(qrow + (size_t)j * D);
        #pragma unroll
        for (int q = 0; q < 4; ++q) {
            float4 v1 = r1[q], v0 = r0[q];
            sy[j * SY_STRIDE + 4*q + 0] = v1.x - v0.x;
            sy[j * SY_STRIDE + 4*q + 1] = v1.y - v0.y;
            sy[j * SY_STRIDE + 4*q + 2] = v1.z - v0.z;
            sy[j * SY_STRIDE + 4*q + 3] = v1.w - v0.w;
        }
    }

    // This lane's 2 dX rows (grid rows 128w+2l+1, +2 -> dX idx 128w+2l, +1).
    v2f xr0[8], xr1[8];
    {
        const int gi0 = 128 * w + 2 * l;           // always <= 510
        int gi1 = gi0 + 1; if (gi1 > 510) gi1 = 510;  // wave3 lane63 fake row
        const float4* p1 = (const float4*)(prow + (size_t)(gi0 + 1) * D);
        const float4* p0 = (const float4*)(prow + (size_t)gi0 * D);
        const float4* q1 = (const float4*)(prow + (size_t)(gi1 + 1) * D);
        const float4* q0 = (const float4*)(prow + (size_t)gi1 * D);
        #pragma unroll
        for (int q = 0; q < 4; ++q) {
            float4 a1 = p1[q], a0 = p0[q];
            float4 b1 = q1[q], b0 = q0[q];
            v2f t;
            t[0] = a1.x - a0.x; t[1] = a1.y - a0.y; xr0[2*q + 0] = t;
            t[0] = a1.z - a0.z; t[1] = a1.w - a0.w; xr0[2*q + 1] = t;
            t[0] = b1.x - b0.x; t[1] = b1.y - b0.y; xr1[2*q + 0] = t;
            t[0] = b1.z - b0.z; t[1] = b1.w - b0.w; xr1[2*q + 1] = t;
        }
    }
    __syncthreads();

    const float* rprev = (w > 0) ? relay[w - 1] : relay[0];  // w=0 never reads

    float kleft0 = 1.f, kleft1 = 1.f;
    float arrived  = 1.f;   // K[top-1][c] for the upcoming step
    float arrivedP = 1.f;   // K[top-1][c-1]

    v2f yA[8], yB[8];
    {   // preload y for local step 0 (column 1 - l, clamped)
        int cc = 1 - l; cc = cc < 1 ? 1 : cc;
        const float* yp = sy + (size_t)(cc - 1) * SY_STRIDE;
        #pragma unroll
        for (int q = 0; q < 8; ++q) yA[q] = *(const v2f*)(yp + 2 * q);
    }

#define STEPB(S, YC, YN) do {                                                  \
        const int c_ = (S) - l + 1;                                            \
        /* prefetch y row for column c_+1 (consumed next step) */              \
        { int cn_ = c_ + 1; cn_ = cn_ < 1 ? 1 : (cn_ > MI ? MI : cn_);         \
          const float* yp_ = sy + (size_t)(cn_ - 1) * SY_STRIDE;               \
          _Pragma("unroll")                                                    \
          for (int q_ = 0; q_ < 8; ++q_) YN[q_] = *(const v2f*)(yp_ + 2*q_); } \
        /* uniform relay fetch: lane0's arrived for next step = col S+2 */     \
        float smn_ = 1.f;                                                      \
        if (w > 0) { int si_ = (S) + 2; if (si_ > MI) si_ = MI;                \
                     smn_ = rprev[si_ & 255]; }                                \
        __builtin_amdgcn_sched_barrier(0);  /* pin loads at step top */        \
        /* branchless boundary fixes */                                        \
        const bool at1_ = (c_ == 1);                                           \
        kleft0 = at1_ ? 1.f : kleft0;                                          \
        kleft1 = at1_ ? 1.f : kleft1;                                          \
        arrivedP = (c_ <= 1) ? 1.f : arrivedP;                                 \
        /* two dot products (2-way ILP, packed f32) */                         \
        float d0_, d1_;                                                        \
        { v2f a0_; a0_[0] = -1.f; a0_[1] = 0.f; v2f a1_ = a0_;                 \
          _Pragma("unroll")                                                    \
          for (int q_ = 0; q_ < 8; ++q_) {                                     \
            a0_ = __builtin_elementwise_fma(xr0[q_], YC[q_], a0_);             \
            a1_ = __builtin_elementwise_fma(xr1[q_], YC[q_], a1_);             \
          }                                                                    \
          d0_ = a0_[0] + a0_[1]; d1_ = a1_[0] + a1_[1]; }                      \
        /* recurrence down the 2 rows */                                       \
        { float kd0_ = kleft0;                                                 \
          kleft0 = fmaf(arrivedP, d0_, arrived + kleft0);                      \
          kleft1 = fmaf(kd0_, d1_, kleft0 + kleft1); }                         \
        /* relay write: wave w bottom row at column c_ */                      \
        if (w < 3 && l == 63 && (unsigned)(c_ - 1) < 511u)                     \
            relay[w][c_ & 255] = kleft1;                                       \
        /* advance arrived pipeline (shfl issued post-compute, 1-step slack)*/ \
        arrivedP = arrived;                                                    \
        { float inc_ = __shfl_up(kleft1, 1, 64);                               \
          arrived = (l == 0) ? ((w > 0) ? smn_ : 1.f) : inc_; }                \
    } while (0)

    for (int pg = 0; pg < NPHASES; ++pg) {
        const int s0 = pg * B_PH - w * OFF_STEPS;
        if (s0 == 0 && w > 0) {
            // first active phase: arrived for step 0 (lane0 col 1)
            float r1 = rprev[1];
            if (l == 0) arrived = r1;
        }
        if (s0 + B_PH > 0 && s0 < NSTEPS) {
            for (int b = 0; b < B_PH; b += 2) {
                const int s = s0 + b;
                if ((unsigned)s < (unsigned)NSTEPS)       STEPB(s,     yA, yB);
                if ((unsigned)(s + 1) < (unsigned)NSTEPS) STEPB(s + 1, yB, yA);
            }
        }
        __syncthreads();
    }
#undef STEPB

    // K[511][511] = wave 3, lane 63, first row (grid row 511).
    if (tid == 255) out[idx] = kleft0;
}

__global__ void sig_reduce_kernel(const float* __restrict__ ws,
                                  float* __restrict__ out) {
    const int a = threadIdx.x;  // 128 threads
    float v = ws[a] + ws[128 + a] - 2.0f * ws[256 + a];
    #pragma unroll
    for (int off = 32; off >= 1; off >>= 1) v += __shfl_down(v, off, 64);
    __shared__ float partial[2];
    if ((a & 63) == 0) partial[a >> 6] = v;
    __syncthreads();
    if (a == 0) out[0] = (partial[0] + partial[1]) * (1.0f / 128.0f);
}

extern "C" void kernel_launch(void* const* d_in, const int* in_sizes, int n_in,
                              void* d_out, int out_size, void* d_ws, size_t ws_size,
                              hipStream_t stream) {
    const float* X = (const float*)d_in[0];
    const float* Y = (const float*)d_in[1];
    float* out = (float*)d_out;
    float* ws  = (float*)d_ws;   // 384 floats: [pair*128 + a]

    sig_pde_kernel<<<dim3(384), dim3(256), 0, stream>>>(X, Y, ws);
    sig_reduce_kernel<<<dim3(1), dim3(128), 0, stream>>>(ws, out);
}

// Round 8
// 125.485 us; speedup vs baseline: 1.7801x; 1.6518x over previous
//
#include <hip/hip_runtime.h>

#define D 16
#define NROW 511                 // interior rows/cols of K grid

typedef float v2f __attribute__((ext_vector_type(2)));

// ---- DPP helpers (wave64) ----
template<int CTRL, int RMASK, bool BC>
__device__ __forceinline__ float dpp_add(float x) {
    int t = __builtin_amdgcn_update_dpp(0, __float_as_int(x), CTRL, RMASK, 0xF, BC);
    return x + __int_as_float(t);
}

// inclusive scan across 64 lanes (rocPRIM pattern)
__device__ __forceinline__ float wave_iscan(float x) {
    x = dpp_add<0x111, 0xF, true >(x);   // row_shr:1
    x = dpp_add<0x112, 0xF, true >(x);   // row_shr:2
    x = dpp_add<0x114, 0xF, true >(x);   // row_shr:4
    x = dpp_add<0x118, 0xF, true >(x);   // row_shr:8
    x = dpp_add<0x142, 0xA, false>(x);   // row_bcast:15 -> rows 1,3
    x = dpp_add<0x143, 0xC, false>(x);   // row_bcast:31 -> rows 2,3
    return x;
}

// shift value from lane l-1 (lane 0 gets 0)
__device__ __forceinline__ float wave_shr1(float x) {
    int t = __builtin_amdgcn_update_dpp(0, __float_as_int(x), 0x138, 0xF, 0xF, true);
    return __int_as_float(t);
}

// One wave per (pair, batch) problem. Row-scan formulation:
//   t[j]    = K[i-1][j] + K[i-1][j-1]*(inc[i][j]-1)
//   K[i][j] = 1 + sum_{u<=j} t[u]        (inclusive scan along the row)
// Lane l owns columns j = 8l..8l+7 (j=0 is the boundary slot, t=0).
// dQ (column diffs) live in registers for the whole kernel; dP (row diffs)
// stream from LDS one row ahead (uniform broadcast reads).
__global__ __launch_bounds__(64, 1)
void sig_pde_kernel(const float* __restrict__ X, const float* __restrict__ Y,
                    float* __restrict__ out) {
    __shared__ float sdx[NROW * D];      // dP rows, 32.7 KB

    const int idx  = blockIdx.x;
    const int pair = idx >> 7;           // 0: XX, 1: YY, 2: XY
    const int a    = idx & 127;
    const float* Pp = (pair == 1) ? Y : X;   // row operand
    const float* Qp = (pair == 0) ? X : Y;   // column operand
    const float* prow = Pp + (size_t)a * 512 * D;
    const float* qrow = Qp + (size_t)a * 512 * D;

    const int l = threadIdx.x;

    // Stage dP rows into LDS (one-time).
    for (int r = l; r < NROW; r += 64) {
        const float4* p1 = (const float4*)(prow + (size_t)(r + 1) * D);
        const float4* p0 = (const float4*)(prow + (size_t)r * D);
        float4* dst = (float4*)(sdx + r * D);
        #pragma unroll
        for (int q = 0; q < 4; ++q) {
            float4 v1 = p1[q], v0 = p0[q];
            float4 dd;
            dd.x = v1.x - v0.x; dd.y = v1.y - v0.y;
            dd.z = v1.z - v0.z; dd.w = v1.w - v0.w;
            dst[q] = dd;
        }
    }

    // Per-lane column diffs: dyr[m] = dQ[8l+m-1], m=0..7 (lane0 m0 unused).
    v2f dyr[8][8];
    {
        int r0 = 8 * l - 1; if (r0 < 0) r0 = 0;
        const float4* pr = (const float4*)(qrow + (size_t)r0 * D);
        float4 p0 = pr[0], p1 = pr[1], p2 = pr[2], p3 = pr[3];
        #pragma unroll
        for (int m = 0; m < 8; ++m) {
            const float4* cr = (const float4*)(qrow + (size_t)(8 * l + m) * D);
            float4 c0 = cr[0], c1 = cr[1], c2 = cr[2], c3 = cr[3];
            v2f t;
            t[0] = c0.x - p0.x; t[1] = c0.y - p0.y; dyr[m][0] = t;
            t[0] = c0.z - p0.z; t[1] = c0.w - p0.w; dyr[m][1] = t;
            t[0] = c1.x - p1.x; t[1] = c1.y - p1.y; dyr[m][2] = t;
            t[0] = c1.z - p1.z; t[1] = c1.w - p1.w; dyr[m][3] = t;
            t[0] = c2.x - p2.x; t[1] = c2.y - p2.y; dyr[m][4] = t;
            t[0] = c2.z - p2.z; t[1] = c2.w - p2.w; dyr[m][5] = t;
            t[0] = c3.x - p3.x; t[1] = c3.y - p3.y; dyr[m][6] = t;
            t[0] = c3.z - p3.z; t[1] = c3.w - p3.w; dyr[m][7] = t;
            p0 = c0; p1 = c1; p2 = c2; p3 = c3;
        }
    }
    __syncthreads();

    float K[8];
    #pragma unroll
    for (int m = 0; m < 8; ++m) K[m] = 1.0f;   // row 0 boundary

    v2f dxbA[8], dxbB[8];
    #pragma unroll
    for (int q = 0; q < 8; ++q) dxbA[q] = ((const v2f*)sdx)[q];   // dX row 0

#define PREF(BUF, RI) do {                                                    \
        const v2f* sp_ = (const v2f*)(sdx + (size_t)(RI) * D);                \
        _Pragma("unroll")                                                     \
        for (int q_ = 0; q_ < 8; ++q_) BUF[q_] = sp_[q_];                     \
    } while (0)

/* force the prefetch to complete here (LDS returns in-order per wave, so
   waiting on the last element covers all 8 loads) */
#define TOUCH(BUF) do { float tt_ = BUF[7][1];                                \
        asm volatile("" : "+v"(tt_)); BUF[7][1] = tt_; } while (0)

#define ROW(DXB) do {                                                         \
        float e_[8], t_[8], s_[8];                                            \
        _Pragma("unroll")                                                     \
        for (int m_ = 0; m_ < 8; ++m_) {                                      \
            v2f acc_; acc_[0] = -1.0f; acc_[1] = 0.0f;                        \
            _Pragma("unroll")                                                 \
            for (int q_ = 0; q_ < 8; ++q_)                                    \
                acc_ = __builtin_elementwise_fma(dyr[m_][q_], DXB[q_], acc_); \
            e_[m_] = acc_[0] + acc_[1];       /* inc - 1 */                   \
        }                                                                     \
        float ksh_ = wave_shr1(K[7]);         /* K[i-1][8l-1] */              \
        t_[0] = fmaf(ksh_, e_[0], K[0]);                                      \
        if (l == 0) t_[0] = 0.0f;             /* j=0 boundary slot */         \
        _Pragma("unroll")                                                     \
        for (int m_ = 1; m_ < 8; ++m_) t_[m_] = fmaf(K[m_-1], e_[m_], K[m_]); \
        s_[0] = t_[0];                                                        \
        _Pragma("unroll")                                                     \
        for (int m_ = 1; m_ < 8; ++m_) s_[m_] = s_[m_-1] + t_[m_];            \
        float S_ = s_[7];                                                     \
        float W_ = wave_iscan(S_);            /* inclusive over lanes */      \
        float base_ = 1.0f + (W_ - S_);       /* 1 + exclusive prefix */      \
        _Pragma("unroll")                                                     \
        for (int m_ = 0; m_ < 8; ++m_) K[m_] = base_ + s_[m_];                \
    } while (0)

    for (int i = 1; i < NROW; i += 2) {    // i = 1,3,...,509
        PREF(dxbB, i);                     // dX[i]   -> for row i+1
        ROW(dxbA);                         // row i    (uses dX[i-1])
        TOUCH(dxbB);
        PREF(dxbA, i + 1);                 // dX[i+1] -> for row i+2 (<=510)
        ROW(dxbB);                         // row i+1  (uses dX[i])
        TOUCH(dxbA);
    }
    ROW(dxbA);                             // row 511 (uses dX[510])

#undef ROW
#undef PREF
#undef TOUCH

    // K[511][511] = lane 63, slot 7.
    if (l == 63) out[idx] = K[7];
}

__global__ void sig_reduce_kernel(const float* __restrict__ ws,
                                  float* __restrict__ out) {
    const int a = threadIdx.x;  // 128 threads
    float v = ws[a] + ws[128 + a] - 2.0f * ws[256 + a];
    #pragma unroll
    for (int off = 32; off >= 1; off >>= 1) v += __shfl_down(v, off, 64);
    __shared__ float partial[2];
    if ((a & 63) == 0) partial[a >> 6] = v;
    __syncthreads();
    if (a == 0) out[0] = (partial[0] + partial[1]) * (1.0f / 128.0f);
}

extern "C" void kernel_launch(void* const* d_in, const int* in_sizes, int n_in,
                              void* d_out, int out_size, void* d_ws, size_t ws_size,
                              hipStream_t stream) {
    const float* X = (const float*)d_in[0];
    const float* Y = (const float*)d_in[1];
    float* out = (float*)d_out;
    float* ws  = (float*)d_ws;   // 384 floats: [pair*128 + a]

    sig_pde_kernel<<<dim3(384), dim3(64), 0, stream>>>(X, Y, ws);
    sig_reduce_kernel<<<dim3(1), dim3(128), 0, stream>>>(ws, out);
}

// Round 9
// 109.861 us; speedup vs baseline: 2.0333x; 1.1422x over previous
//
#include <hip/hip_runtime.h>

#define D 16
#define NROW 511

typedef short bf16x8 __attribute__((ext_vector_type(8)));
typedef float f32x16 __attribute__((ext_vector_type(16)));

// ---- DPP helpers (wave64), verified in round 8 ----
template<int CTRL, int RMASK, bool BC>
__device__ __forceinline__ float dpp_add(float x) {
    int t = __builtin_amdgcn_update_dpp(0, __float_as_int(x), CTRL, RMASK, 0xF, BC);
    return x + __int_as_float(t);
}
__device__ __forceinline__ float wave_iscan(float x) {
    x = dpp_add<0x111, 0xF, true >(x);   // row_shr:1
    x = dpp_add<0x112, 0xF, true >(x);   // row_shr:2
    x = dpp_add<0x114, 0xF, true >(x);   // row_shr:4
    x = dpp_add<0x118, 0xF, true >(x);   // row_shr:8
    x = dpp_add<0x142, 0xA, false>(x);   // row_bcast:15
    x = dpp_add<0x143, 0xC, false>(x);   // row_bcast:31
    return x;
}
__device__ __forceinline__ float wave_shr1(float x) {
    int t = __builtin_amdgcn_update_dpp(0, __float_as_int(x), 0x138, 0xF, 0xF, true);
    return __int_as_float(t);
}

// f32 -> bf16 with round-to-nearest-even
__device__ __forceinline__ short f2bf(float f) {
    unsigned u = __float_as_uint(f);
    unsigned r = u + 0x7FFFu + ((u >> 16) & 1u);
    return (short)(r >> 16);
}

// One wave per (pair,batch). For each 32-row block: 16x mfma_32x32x16_bf16
// produce inc[32][512] (f32, swizzled) in LDS; then the verified row-scan
// (t/s/iscan) consumes it. B-fragments (all of dY) stay in 64 VGPRs.
__global__ __launch_bounds__(64, 1)
void sig_pde_kernel(const float* __restrict__ X, const float* __restrict__ Y,
                    float* __restrict__ out) {
    __shared__ float sinc[32 * 512];        // 64 KB inc block, swizzled

    const int idx  = blockIdx.x;
    const int pair = idx >> 7;              // 0: XX, 1: YY, 2: XY
    const int a    = idx & 127;
    const float* Pp = (pair == 1) ? Y : X;  // row operand (dX)
    const float* Qp = (pair == 0) ? X : Y;  // col operand (dY)
    const float* prow = Pp + (size_t)a * 512 * D;
    const float* qrow = Qp + (size_t)a * 512 * D;

    const int l  = threadIdx.x;
    const int lm = l & 31;
    const int kh = l >> 5;                  // K-half of the fragment
    const int d0 = kh * 8;                  // this lane's dim offset

    // ---- B fragments: 16 column tiles of dY, resident in registers ----
    // B[k=(l>>5)*8+e][col=32n+(l&31)] ; col j uses dY[j-1] (j=0 is garbage)
    bf16x8 Bf[16];
    #pragma unroll
    for (int n = 0; n < 16; ++n) {
        int jj = 32 * n + lm - 1;
        if (jj < 0) jj = 0;
        const float4* y1 = (const float4*)(qrow + (size_t)(jj + 1) * D + d0);
        const float4* y0 = (const float4*)(qrow + (size_t)jj * D + d0);
        float4 h1 = y1[0], h0 = y0[0], g1 = y1[1], g0 = y0[1];
        bf16x8 f;
        f[0] = f2bf(h1.x - h0.x); f[1] = f2bf(h1.y - h0.y);
        f[2] = f2bf(h1.z - h0.z); f[3] = f2bf(h1.w - h0.w);
        f[4] = f2bf(g1.x - g0.x); f[5] = f2bf(g1.y - g0.y);
        f[6] = f2bf(g1.z - g0.z); f[7] = f2bf(g1.w - g0.w);
        Bf[n] = f;
    }

    // A-fragment for row block b: A[row=32b+(l&31)][k=(l>>5)*8+e] = dX[row-1]
    auto loadA = [&](int b) -> bf16x8 {
        int ii = 32 * b + lm - 1;
        if (ii < 0) ii = 0;                 // row 0 is garbage (never scanned)
        const float4* x1 = (const float4*)(prow + (size_t)(ii + 1) * D + d0);
        const float4* x0 = (const float4*)(prow + (size_t)ii * D + d0);
        float4 h1 = x1[0], h0 = x0[0], g1 = x1[1], g0 = x0[1];
        bf16x8 f;
        f[0] = f2bf(h1.x - h0.x); f[1] = f2bf(h1.y - h0.y);
        f[2] = f2bf(h1.z - h0.z); f[3] = f2bf(h1.w - h0.w);
        f[4] = f2bf(g1.x - g0.x); f[5] = f2bf(g1.y - g0.y);
        f[6] = f2bf(g1.z - g0.z); f[7] = f2bf(g1.w - g0.w);
        return f;
    };

    float K[8];
    #pragma unroll
    for (int m = 0; m < 8; ++m) K[m] = 1.0f;

    const int rot = (l >> 2) & 7;           // read-side swizzle rotation
    float* wbase = sinc + kh * 2048;        // +4 rows for upper half-wave

    bf16x8 Acur = loadA(0);

    for (int b = 0; b < 16; ++b) {
        // ---- GEMM phase: inc rows 32b..32b+31, all 512 cols ----
        #pragma unroll
        for (int n = 0; n < 16; ++n) {
            f32x16 acc = {0.f,0.f,0.f,0.f,0.f,0.f,0.f,0.f,
                          0.f,0.f,0.f,0.f,0.f,0.f,0.f,0.f};
            acc = __builtin_amdgcn_mfma_f32_32x32x16_bf16(Acur, Bf[n], acc, 0, 0, 0);
            // C layout: col = 32n+(l&31), row = (r&3) + 8*(r>>2) + 4*(l>>5)
            // swizzled store: word = row*512 + (c&~7) + (((c&7)+(c>>5))&7)
            float* p = wbase + 32 * n + (lm & ~7) + (((l & 7) + n) & 7);
            #pragma unroll
            for (int r = 0; r < 16; ++r)
                p[(r & 3) * 512 + (r >> 2) * 4096] = acc[r];
        }
        if (b < 15) Acur = loadA(b + 1);    // prefetch next A under the scan

        // ---- scan phase: rows of this block (verified round-8 logic) ----
        const float* rbase = sinc + 8 * l;
        for (int r = (b == 0 ? 1 : 0); r < 32; ++r) {
            const float* rp = rbase + r * 512;
            float e[8];
            #pragma unroll
            for (int m = 0; m < 8; ++m)
                e[m] = rp[(m + rot) & 7] - 1.0f;   // inc[i][8l+m] - 1
            float ksh = wave_shr1(K[7]);           // K[i-1][8l-1]
            float t0 = fmaf(ksh, e[0], K[0]);
            if (l == 0) t0 = 0.0f;                 // j=0 boundary slot
            float t1 = fmaf(K[0], e[1], K[1]);
            float t2 = fmaf(K[1], e[2], K[2]);
            float t3 = fmaf(K[2], e[3], K[3]);
            float t4 = fmaf(K[3], e[4], K[4]);
            float t5 = fmaf(K[4], e[5], K[5]);
            float t6 = fmaf(K[5], e[6], K[6]);
            float t7 = fmaf(K[6], e[7], K[7]);
            float s0 = t0,      s1 = s0 + t1, s2 = s1 + t2, s3 = s2 + t3;
            float s4 = s3 + t4, s5 = s4 + t5, s6 = s5 + t6, s7 = s6 + t7;
            float W    = wave_iscan(s7);
            float base = 1.0f + (W - s7);          // 1 + exclusive prefix
            K[0] = base + s0; K[1] = base + s1; K[2] = base + s2; K[3] = base + s3;
            K[4] = base + s4; K[5] = base + s5; K[6] = base + s6; K[7] = base + s7;
        }
    }

    // K[511][511] = lane 63, slot 7
    if (l == 63) out[idx] = K[7];
}

__global__ void sig_reduce_kernel(const float* __restrict__ ws,
                                  float* __restrict__ out) {
    const int a = threadIdx.x;  // 128 threads
    float v = ws[a] + ws[128 + a] - 2.0f * ws[256 + a];
    #pragma unroll
    for (int off = 32; off >= 1; off >>= 1) v += __shfl_down(v, off, 64);
    __shared__ float partial[2];
    if ((a & 63) == 0) partial[a >> 6] = v;
    __syncthreads();
    if (a == 0) out[0] = (partial[0] + partial[1]) * (1.0f / 128.0f);
}

extern "C" void kernel_launch(void* const* d_in, const int* in_sizes, int n_in,
                              void* d_out, int out_size, void* d_ws, size_t ws_size,
                              hipStream_t stream) {
    const float* X = (const float*)d_in[0];
    const float* Y = (const float*)d_in[1];
    float* out = (float*)d_out;
    float* ws  = (float*)d_ws;   // 384 floats: [pair*128 + a]

    sig_pde_kernel<<<dim3(384), dim3(64), 0, stream>>>(X, Y, ws);
    sig_reduce_kernel<<<dim3(1), dim3(128), 0, stream>>>(ws, out);
}

// Round 10
// 94.034 us; speedup vs baseline: 2.3755x; 1.1683x over previous
//
#include <hip/hip_runtime.h>

#define D 16

typedef short bf16x8 __attribute__((ext_vector_type(8)));
typedef float f32x16 __attribute__((ext_vector_type(16)));

// ---- DPP helpers (wave64), verified rounds 8-9 ----
template<int CTRL, int RMASK, bool BC>
__device__ __forceinline__ float dpp_add(float x) {
    int t = __builtin_amdgcn_update_dpp(0, __float_as_int(x), CTRL, RMASK, 0xF, BC);
    return x + __int_as_float(t);
}
__device__ __forceinline__ float wave_iscan(float x) {
    x = dpp_add<0x111, 0xF, true >(x);   // row_shr:1
    x = dpp_add<0x112, 0xF, true >(x);   // row_shr:2
    x = dpp_add<0x114, 0xF, true >(x);   // row_shr:4
    x = dpp_add<0x118, 0xF, true >(x);   // row_shr:8
    x = dpp_add<0x142, 0xA, false>(x);   // row_bcast:15
    x = dpp_add<0x143, 0xC, false>(x);   // row_bcast:31
    return x;
}
__device__ __forceinline__ float wave_shr1(float x) {
    int t = __builtin_amdgcn_update_dpp(0, __float_as_int(x), 0x138, 0xF, 0xF, true);
    return __int_as_float(t);
}

// f32 -> bf16 round-to-nearest-even
__device__ __forceinline__ short f2bf(float f) {
    unsigned u = __float_as_uint(f);
    unsigned r = u + 0x7FFFu + ((u >> 16) & 1u);
    return (short)(r >> 16);
}

// One wave per (pair,batch). Per 32-row block: 16x mfma_32x32x16_bf16
// produce (inc-1)[32][512] (f32, col-rot swizzled) in LDS; the row-scan
// consumes it with a double-buffered e-prefetch pipeline (round-8 pattern).
__global__ __launch_bounds__(64, 1)
void sig_pde_kernel(const float* __restrict__ X, const float* __restrict__ Y,
                    float* __restrict__ out) {
    __shared__ float sinc[32 * 512];        // 64 KB (inc-1) block, swizzled

    const int idx  = blockIdx.x;
    const int pair = idx >> 7;              // 0: XX, 1: YY, 2: XY
    const int a    = idx & 127;
    const float* Pp = (pair == 1) ? Y : X;  // row operand (dX)
    const float* Qp = (pair == 0) ? X : Y;  // col operand (dY)
    const float* prow = Pp + (size_t)a * 512 * D;
    const float* qrow = Qp + (size_t)a * 512 * D;

    const int l  = threadIdx.x;
    const int lm = l & 31;
    const int kh = l >> 5;                  // K-half of the fragment
    const int d0 = kh * 8;                  // this lane's dim offset

    // ---- B fragments: 16 column tiles of dY, resident in registers ----
    bf16x8 Bf[16];
    #pragma unroll
    for (int n = 0; n < 16; ++n) {
        int jj = 32 * n + lm - 1;
        if (jj < 0) jj = 0;                 // col 0 garbage (masked in scan)
        const float4* y1 = (const float4*)(qrow + (size_t)(jj + 1) * D + d0);
        const float4* y0 = (const float4*)(qrow + (size_t)jj * D + d0);
        float4 h1 = y1[0], h0 = y0[0], g1 = y1[1], g0 = y0[1];
        bf16x8 f;
        f[0] = f2bf(h1.x - h0.x); f[1] = f2bf(h1.y - h0.y);
        f[2] = f2bf(h1.z - h0.z); f[3] = f2bf(h1.w - h0.w);
        f[4] = f2bf(g1.x - g0.x); f[5] = f2bf(g1.y - g0.y);
        f[6] = f2bf(g1.z - g0.z); f[7] = f2bf(g1.w - g0.w);
        Bf[n] = f;
    }

    auto loadA = [&](int b) -> bf16x8 {
        int ii = 32 * b + lm - 1;
        if (ii < 0) ii = 0;                 // row 0 garbage (never scanned)
        const float4* x1 = (const float4*)(prow + (size_t)(ii + 1) * D + d0);
        const float4* x0 = (const float4*)(prow + (size_t)ii * D + d0);
        float4 h1 = x1[0], h0 = x0[0], g1 = x1[1], g0 = x0[1];
        bf16x8 f;
        f[0] = f2bf(h1.x - h0.x); f[1] = f2bf(h1.y - h0.y);
        f[2] = f2bf(h1.z - h0.z); f[3] = f2bf(h1.w - h0.w);
        f[4] = f2bf(g1.x - g0.x); f[5] = f2bf(g1.y - g0.y);
        f[6] = f2bf(g1.z - g0.z); f[7] = f2bf(g1.w - g0.w);
        return f;
    };

    float K[8];
    #pragma unroll
    for (int m = 0; m < 8; ++m) K[m] = 1.0f;

    const int rot = (l >> 2) & 7;           // read-side rotation (0-conflict)
    float* wbase = sinc + kh * 2048;        // +4 rows for upper half-wave

    // per-lane element byte offsets within a tile row (constant all kernel)
    int ea4[8];
    #pragma unroll
    for (int m = 0; m < 8; ++m) ea4[m] = (8 * l + ((m + rot) & 7)) * 4;

    float eA[8], eB[8];

#define PREF(BUF, RB) do {                                                    \
        const char* pb_ = (const char*)sinc + (RB);                           \
        _Pragma("unroll")                                                     \
        for (int m_ = 0; m_ < 8; ++m_)                                        \
            BUF[m_] = *(const float*)(pb_ + ea4[m_]);                         \
    } while (0)

#define TOUCH(BUF) do { float tt_ = BUF[7];                                   \
        asm volatile("" : "+v"(tt_)); BUF[7] = tt_; } while (0)

#define ROW(E) do {                                                           \
        float ksh_ = wave_shr1(K[7]);          /* K[i-1][8l-1] */             \
        float t0_ = fmaf(ksh_, E[0], K[0]);                                   \
        t0_ = (l == 0) ? 0.0f : t0_;           /* j=0 boundary slot */        \
        float t1_ = fmaf(K[0], E[1], K[1]);                                   \
        float t2_ = fmaf(K[1], E[2], K[2]);                                   \
        float t3_ = fmaf(K[2], E[3], K[3]);                                   \
        float t4_ = fmaf(K[3], E[4], K[4]);                                   \
        float t5_ = fmaf(K[4], E[5], K[5]);                                   \
        float t6_ = fmaf(K[5], E[6], K[6]);                                   \
        float t7_ = fmaf(K[6], E[7], K[7]);                                   \
        float s0_ = t0_,       s1_ = s0_ + t1_, s2_ = s1_ + t2_;              \
        float s3_ = s2_ + t3_, s4_ = s3_ + t4_, s5_ = s4_ + t5_;              \
        float s6_ = s5_ + t6_, s7_ = s6_ + t7_;                               \
        float W_    = wave_iscan(s7_);                                        \
        float base_ = 1.0f + (W_ - s7_);       /* 1 + exclusive prefix */     \
        K[0] = base_ + s0_; K[1] = base_ + s1_;                               \
        K[2] = base_ + s2_; K[3] = base_ + s3_;                               \
        K[4] = base_ + s4_; K[5] = base_ + s5_;                               \
        K[6] = base_ + s6_; K[7] = base_ + s7_;                               \
    } while (0)

// rows FROM..31 with e-prefetch pipeline; (30-FROM) must be even
#define SCAN_PAIRS(FROM) do {                                                 \
        int rb_ = (FROM) * 2048;                                              \
        PREF(eA, rb_);                                                        \
        for (; rb_ < 30 * 2048; rb_ += 4096) {                                \
            PREF(eB, rb_ + 2048);                                             \
            ROW(eA);                                                          \
            TOUCH(eB);                                                        \
            PREF(eA, rb_ + 4096);                                             \
            ROW(eB);                                                          \
            TOUCH(eA);                                                        \
        }                                                                     \
        PREF(eB, 31 * 2048);      /* final pair: rows 30,31 */                \
        ROW(eA);                                                              \
        TOUCH(eB);                                                            \
        ROW(eB);                                                              \
    } while (0)

    bf16x8 Acur = loadA(0);

    for (int b = 0; b < 16; ++b) {
        // ---- GEMM phase: (inc-1) rows 32b..32b+31, all 512 cols ----
        #pragma unroll
        for (int n = 0; n < 16; ++n) {
            f32x16 acc = {-1.f,-1.f,-1.f,-1.f,-1.f,-1.f,-1.f,-1.f,
                          -1.f,-1.f,-1.f,-1.f,-1.f,-1.f,-1.f,-1.f};
            acc = __builtin_amdgcn_mfma_f32_32x32x16_bf16(Acur, Bf[n], acc, 0, 0, 0);
            float* p = wbase + 32 * n + (lm & ~7) + (((l & 7) + n) & 7);
            #pragma unroll
            for (int r = 0; r < 16; ++r)
                p[(r & 3) * 512 + (r >> 2) * 4096] = acc[r];
        }
        if (b < 15) Acur = loadA(b + 1);    // global prefetch under the scan

        // ---- scan phase ----
        if (b == 0) {
            PREF(eA, 2048);
            ROW(eA);                        // row 1 (one-time exposed latency)
            SCAN_PAIRS(2);
        } else {
            SCAN_PAIRS(0);
        }
    }

#undef SCAN_PAIRS
#undef ROW
#undef TOUCH
#undef PREF

    // K[511][511] = lane 63, slot 7
    if (l == 63) out[idx] = K[7];
}

__global__ void sig_reduce_kernel(const float* __restrict__ ws,
                                  float* __restrict__ out) {
    const int a = threadIdx.x;  // 128 threads
    float v = ws[a] + ws[128 + a] - 2.0f * ws[256 + a];
    #pragma unroll
    for (int off = 32; off >= 1; off >>= 1) v += __shfl_down(v, off, 64);
    __shared__ float partial[2];
    if ((a & 63) == 0) partial[a >> 6] = v;
    __syncthreads();
    if (a == 0) out[0] = (partial[0] + partial[1]) * (1.0f / 128.0f);
}

extern "C" void kernel_launch(void* const* d_in, const int* in_sizes, int n_in,
                              void* d_out, int out_size, void* d_ws, size_t ws_size,
                              hipStream_t stream) {
    const float* X = (const float*)d_in[0];
    const float* Y = (const float*)d_in[1];
    float* out = (float*)d_out;
    float* ws  = (float*)d_ws;   // 384 floats: [pair*128 + a]

    sig_pde_kernel<<<dim3(384), dim3(64), 0, stream>>>(X, Y, ws);
    sig_reduce_kernel<<<dim3(1), dim3(128), 0, stream>>>(ws, out);
}